// Round 2
// baseline (503.465 us; speedup 1.0000x reference)
//
#include <hip/hip_runtime.h>

#define NEG (-10000.0f)
#define START_TAG 62
#define STOP_TAG 63
#define SLEN 512
#define BATCH 512
#define NTAG 64

// One wave per batch; lane j = tag j.
// e[i] = exp(trans[i][j]) held in VGPRs (64 regs) -- launch_bounds(64,1) so the
// compiler has the full 512-VGPR budget (round 1: default bounds -> spilled to
// scratch, VGPR_Count=44, 392us).
// Recursion in "scaled linear space": p_i = exp(alpha_i - C); acc_j = sum_i p_i*E_ij;
// alpha'_j = C + log(acc_j) + f_j.  C cancels exactly, so we may use a ONE-STEP-STALE
// wave max for C: the shuffle butterfly runs concurrently with the dot product instead
// of serializing exp->dot->log->butterfly->exp. Staleness bounds p <= e^14 (fp32-safe).
// p broadcast via LDS same-address reads: 1 ds_write_b32 + 16 ds_read_b128 (+64 fmac)
// instead of 64 readlane + 64 fma.
__global__ __launch_bounds__(64, 1) void crf_fwd(const float* __restrict__ feats,
                                                 const int* __restrict__ tags,
                                                 const float* __restrict__ mask,
                                                 const float* __restrict__ trans,
                                                 float* __restrict__ diff /* [BATCH] */) {
    __shared__ float p_lds[NTAG];
    const int b = blockIdx.x;
    const int j = threadIdx.x; // tag lane 0..63

    // ---- E column in registers + column sum (for exact analytic step 0) ----
    float e[NTAG];
    float colsum = 0.0f;
#pragma unroll
    for (int i = 0; i < NTAG; ++i) {
        e[i] = __expf(trans[i * NTAG + j]); // exp(NEG) underflows to exactly 0 - desired
        colsum += e[i];
    }
    const float tstop = trans[STOP_TAG * NTAG + j];

    // ---- step 0 (exact analytic; trans[START,:]==NEG so alpha1 = NEG+log1p(colsum)+f) ----
    float f_cur = feats[(0 * BATCH + b) * NTAG + j];
    float m0 = mask[0 * BATCH + b];
    float alpha = (m0 > 0.0f) ? (NEG + log1pf(colsum) + f_cur)
                              : ((j == START_TAG) ? 0.0f : NEG);

    // ---- true-path score, s = 0 ----
    int tc0 = __builtin_amdgcn_readfirstlane(tags[0 * BATCH + b]);
    float em0 = __uint_as_float(__builtin_amdgcn_readlane(__float_as_uint(f_cur), tc0));
    float score = (em0 + trans[START_TAG * NTAG + tc0]) * m0;
    float msum = m0;

    // C for iteration 1: exact max of alpha (thereafter one-step stale)
    float C = alpha;
#pragma unroll
    for (int w = 32; w >= 1; w >>= 1)
        C = fmaxf(C, __shfl_xor(C, w, 64));

    // prefetch s = 1 (incl. the score-path transition trans[tags[0]][tags[1]])
    float f_next = feats[(1 * BATCH + b) * NTAG + j];
    int tc_next = __builtin_amdgcn_readfirstlane(tags[1 * BATCH + b]);
    float mk_next = mask[1 * BATCH + b];
    float trv_next = trans[tc0 * NTAG + tc_next];

    for (int s = 1; s < SLEN; ++s) {
        f_cur = f_next;
        const float mk = mk_next;
        const float trv = trv_next;
        const int tcur = tc_next;

        const int sp = (s + 1 < SLEN) ? (s + 1) : (SLEN - 1);
        f_next = feats[(sp * BATCH + b) * NTAG + j];
        tc_next = __builtin_amdgcn_readfirstlane(tags[sp * BATCH + b]);
        mk_next = mask[sp * BATCH + b];
        trv_next = trans[tcur * NTAG + tc_next]; // scalar (SMEM) load, uniform indices

        // ---- critical chain: exp -> LDS broadcast -> dot -> log ----
        float p = __expf(alpha - C); // C one-step stale: p bounded by ~e^14
        p_lds[j] = p;
        const float4* P4 = (const float4*)p_lds;
        float acc0 = 0.0f, acc1 = 0.0f, acc2 = 0.0f, acc3 = 0.0f;
#pragma unroll
        for (int c = 0; c < 16; ++c) {
            float4 q = P4[c]; // same address across lanes -> LDS broadcast, conflict-free
            acc0 = fmaf(q.x, e[4 * c + 0], acc0);
            acc1 = fmaf(q.y, e[4 * c + 1], acc1);
            acc2 = fmaf(q.z, e[4 * c + 2], acc2);
            acc3 = fmaf(q.w, e[4 * c + 3], acc3);
        }
        float acc = (acc0 + acc1) + (acc2 + acc3);

        float nxt = C + __logf(acc) + f_cur; // acc==0 (STOP col) -> -inf, benign
        float alpha_new = (mk > 0.0f) ? nxt : alpha;

        // butterfly max of PRE-update alpha: independent of the dot product above,
        // schedules in parallel; result is next iteration's (stale) C.
        float m = alpha;
#pragma unroll
        for (int w = 32; w >= 1; w >>= 1)
            m = fmaxf(m, __shfl_xor(m, w, 64));

        // true-path score (wave-uniform, off critical path)
        float emv = __uint_as_float(__builtin_amdgcn_readlane(__float_as_uint(f_cur), tcur));
        score = fmaf(emv + trv, mk, score);
        msum += mk;

        alpha = alpha_new;
        C = fmaxf(m, NEG); // guard; still stale-by-one
    }

    // score += trans[last_tag][STOP]
    int last_idx = (int)(msum + 0.5f) - 1;
    int ltag = tags[last_idx * BATCH + b];
    score += trans[ltag * NTAG + STOP_TAG];

    // log_z = logsumexp_j(alpha_j + trans[STOP][j]) -- exact max here
    float v = alpha + tstop;
    float m2 = v;
#pragma unroll
    for (int w = 32; w >= 1; w >>= 1)
        m2 = fmaxf(m2, __shfl_xor(m2, w, 64));
    float pe = __expf(v - m2);
#pragma unroll
    for (int w = 32; w >= 1; w >>= 1)
        pe += __shfl_xor(pe, w, 64);
    float log_z = m2 + __logf(pe);

    if (j == 0) diff[b] = log_z - score;
}

__global__ __launch_bounds__(512) void crf_reduce(const float* __restrict__ diff,
                                                  float* __restrict__ out) {
    __shared__ float sdata[8];
    int t = threadIdx.x;
    float val = diff[t];
#pragma unroll
    for (int w = 32; w >= 1; w >>= 1)
        val += __shfl_xor(val, w, 64);
    if ((t & 63) == 0) sdata[t >> 6] = val;
    __syncthreads();
    if (t == 0) {
        float ssum = 0.0f;
        for (int i = 0; i < 8; ++i) ssum += sdata[i];
        out[0] = ssum * (1.0f / (float)BATCH);
    }
}

extern "C" void kernel_launch(void* const* d_in, const int* in_sizes, int n_in,
                              void* d_out, int out_size, void* d_ws, size_t ws_size,
                              hipStream_t stream) {
    const float* feats = (const float*)d_in[0];
    const int* tags = (const int*)d_in[1];
    const float* mask = (const float*)d_in[2];
    const float* trans = (const float*)d_in[3];
    float* out = (float*)d_out;
    float* diff = (float*)d_ws; // 512 floats

    crf_fwd<<<BATCH, 64, 0, stream>>>(feats, tags, mask, trans, diff);
    crf_reduce<<<1, 512, 0, stream>>>(diff, out);
}

// Round 3
// 340.807 us; speedup vs baseline: 1.4773x; 1.4773x over previous
//
#include <hip/hip_runtime.h>

#define NEG (-10000.0f)
#define START_TAG 62
#define STOP_TAG 63
#define SLEN 512
#define BATCH 512
#define NTAG 64

// One wave per batch; lane j = tag j.
// e[i] = exp(trans[i][j]) held in VGPRs (64 regs). amdgpu_waves_per_eu(1,1)
// pins the occupancy target to 1 wave/EU -> full 512-VGPR budget, no spill
// (rounds 1-2: allocator chose 44/64 VGPRs and spilled e[] to L1-resident
// scratch; occupancy is grid-limited at 512 waves / 6% anyway).
//
// Scaled linear-space recursion: p_i = exp(alpha_i - C); acc_j = sum_i p_i*E_ij;
// alpha'_j = C + log(acc_j) + f_j. C cancels EXACTLY, so no wave-max is needed:
// C = readfirstlane(alpha) (1 SALU op). Post-step-0 cross-lane spread of alpha
// is bounded by spread(trans)+spread(f) ~ +-20, so p in e^[-20,20] - fp32-safe.
// This removes the 6-deep dependent shuffle butterfly (~700 cyc/step at 1
// wave/SIMD) that dominated rounds 1-2.
//
// Dot: 64 v_readlane broadcasts + 64 v_fmac in 4 independent chains -
// issue-bound, zero memory latency on the critical path. No LDS in the loop.
__global__ __launch_bounds__(64) __attribute__((amdgpu_waves_per_eu(1, 1)))
void crf_fwd(const float* __restrict__ feats,
             const int* __restrict__ tags,
             const float* __restrict__ mask,
             const float* __restrict__ trans,
             float* __restrict__ diff /* [BATCH] */) {
    const int b = blockIdx.x;
    const int j = threadIdx.x; // tag lane 0..63

    // ---- E column in registers + column sum (for exact analytic step 0) ----
    float e[NTAG];
    float colsum = 0.0f;
#pragma unroll
    for (int i = 0; i < NTAG; ++i) {
        e[i] = __expf(trans[i * NTAG + j]); // exp(NEG) underflows to exactly 0 - desired
        colsum += e[i];
    }
    const float tstop = trans[STOP_TAG * NTAG + j];

    // ---- step 0 (exact analytic; trans[START,:]==NEG so alpha1 = NEG+log1p(colsum)+f) ----
    float f_cur = feats[(0 * BATCH + b) * NTAG + j];
    float m0 = mask[0 * BATCH + b];
    float alpha = (m0 > 0.0f) ? (NEG + log1pf(colsum) + f_cur)
                              : ((j == START_TAG) ? 0.0f : NEG);

    // ---- true-path score, s = 0 ----
    int tc0 = __builtin_amdgcn_readfirstlane(tags[0 * BATCH + b]);
    float em0 = __uint_as_float(__builtin_amdgcn_readlane(__float_as_uint(f_cur), tc0));
    float score = (em0 + trans[START_TAG * NTAG + tc0]) * m0;
    float msum = m0;

    // prefetch s = 1 (incl. the score-path transition trans[tags[0]][tags[1]])
    float f_next = feats[(1 * BATCH + b) * NTAG + j];
    int tc_next = __builtin_amdgcn_readfirstlane(tags[1 * BATCH + b]);
    float mk_next = mask[1 * BATCH + b];
    float trv_next = trans[tc0 * NTAG + tc_next];

    for (int s = 1; s < SLEN; ++s) {
        f_cur = f_next;
        const float mk = mk_next;
        const float trv = trv_next;
        const int tcur = tc_next;

        const int sp = (s + 1 < SLEN) ? (s + 1) : (SLEN - 1);
        f_next = feats[(sp * BATCH + b) * NTAG + j];
        tc_next = __builtin_amdgcn_readfirstlane(tags[sp * BATCH + b]);
        mk_next = mask[sp * BATCH + b];
        trv_next = trans[tcur * NTAG + tc_next]; // uniform indices -> scalar loads

        // scaling constant: lane 0's alpha (C cancels exactly; only range matters)
        float C = __uint_as_float(__builtin_amdgcn_readfirstlane(__float_as_uint(alpha)));
        float p = __expf(alpha - C); // bounded by e^{+-20} after step 0

        // acc_j = sum_i p_i * E[i][j]; p_i broadcast via readlane, 4 indep chains
        unsigned pu = __float_as_uint(p);
        float acc0 = 0.0f, acc1 = 0.0f, acc2 = 0.0f, acc3 = 0.0f;
#pragma unroll
        for (int i = 0; i < NTAG; i += 4) {
            acc0 = fmaf(__uint_as_float(__builtin_amdgcn_readlane(pu, i + 0)), e[i + 0], acc0);
            acc1 = fmaf(__uint_as_float(__builtin_amdgcn_readlane(pu, i + 1)), e[i + 1], acc1);
            acc2 = fmaf(__uint_as_float(__builtin_amdgcn_readlane(pu, i + 2)), e[i + 2], acc2);
            acc3 = fmaf(__uint_as_float(__builtin_amdgcn_readlane(pu, i + 3)), e[i + 3], acc3);
        }
        float acc = (acc0 + acc1) + (acc2 + acc3);

        float nxt = C + __logf(acc) + f_cur; // acc==0 (STOP col) -> -inf, benign
        alpha = (mk > 0.0f) ? nxt : alpha;

        // true-path score (wave-uniform, off critical path)
        float emv = __uint_as_float(__builtin_amdgcn_readlane(__float_as_uint(f_cur), tcur));
        score = fmaf(emv + trv, mk, score);
        msum += mk;
    }

    // score += trans[last_tag][STOP]
    int last_idx = (int)(msum + 0.5f) - 1;
    int ltag = tags[last_idx * BATCH + b];
    score += trans[ltag * NTAG + STOP_TAG];

    // log_z = logsumexp_j(alpha_j + trans[STOP][j]) -- exact butterfly, once
    float v = alpha + tstop;
    float m2 = v;
#pragma unroll
    for (int w = 32; w >= 1; w >>= 1)
        m2 = fmaxf(m2, __shfl_xor(m2, w, 64));
    float pe = __expf(v - m2);
#pragma unroll
    for (int w = 32; w >= 1; w >>= 1)
        pe += __shfl_xor(pe, w, 64);
    float log_z = m2 + __logf(pe);

    if (j == 0) diff[b] = log_z - score;
}

__global__ __launch_bounds__(512) void crf_reduce(const float* __restrict__ diff,
                                                  float* __restrict__ out) {
    __shared__ float sdata[8];
    int t = threadIdx.x;
    float val = diff[t];
#pragma unroll
    for (int w = 32; w >= 1; w >>= 1)
        val += __shfl_xor(val, w, 64);
    if ((t & 63) == 0) sdata[t >> 6] = val;
    __syncthreads();
    if (t == 0) {
        float ssum = 0.0f;
        for (int i = 0; i < 8; ++i) ssum += sdata[i];
        out[0] = ssum * (1.0f / (float)BATCH);
    }
}

extern "C" void kernel_launch(void* const* d_in, const int* in_sizes, int n_in,
                              void* d_out, int out_size, void* d_ws, size_t ws_size,
                              hipStream_t stream) {
    const float* feats = (const float*)d_in[0];
    const int* tags = (const int*)d_in[1];
    const float* mask = (const float*)d_in[2];
    const float* trans = (const float*)d_in[3];
    float* out = (float*)d_out;
    float* diff = (float*)d_ws; // 512 floats

    crf_fwd<<<BATCH, 64, 0, stream>>>(feats, tags, mask, trans, diff);
    crf_reduce<<<1, 512, 0, stream>>>(diff, out);
}

// Round 4
// 259.835 us; speedup vs baseline: 1.9376x; 1.3116x over previous
//
#include <hip/hip_runtime.h>

#define NEG (-10000.0f)
#define START_TAG 62
#define STOP_TAG 63
#define SLEN 512
#define BATCH 512
#define NTAG 64

// One wave per batch; lane j = tag j.
// e[i] = exp(trans[i][j]) in VGPRs (amdgpu_waves_per_eu(1,1) -> full 512-VGPR
// budget, no spill; verified round 3: VGPR_Count=132, scratch gone).
//
// Hot loop = forward recursion ONLY. Round 3 showed ~1000 stall cyc/step from
// the score path's readfirstlane(tags-load) + dependent scalar trans load
// consuming same-iteration global loads. The score path is time-parallel, so
// it moves to an epilogue where the 64 lanes split the 512 steps (8 gathers
// each, independent, one pipelined latency wait total). feats/mask prefetch
// depth 2: a load issued at step s is consumed at s+2 (~800 cyc later).
//
// Scaled linear-space recursion: p_i = exp(alpha_i - C), acc_j = sum_i p_i*E_ij,
// alpha'_j = C + log(acc_j) + f_j. C cancels exactly -> C = readfirstlane(alpha)
// (no butterfly). Spread of alpha is bounded by spread(trans)+spread(f) ~ +-20.
__global__ __launch_bounds__(64) __attribute__((amdgpu_waves_per_eu(1, 1)))
void crf_fwd(const float* __restrict__ feats,
             const int* __restrict__ tags,
             const float* __restrict__ mask,
             const float* __restrict__ trans,
             float* __restrict__ diff /* [BATCH] */) {
    const int b = blockIdx.x;
    const int j = threadIdx.x; // tag lane 0..63

    // ---- E column in registers + column sum (for exact analytic step 0) ----
    float e[NTAG];
    float colsum = 0.0f;
#pragma unroll
    for (int i = 0; i < NTAG; ++i) {
        e[i] = __expf(trans[i * NTAG + j]); // exp(NEG) underflows to 0 - desired
        colsum += e[i];
    }
    const float tstop = trans[STOP_TAG * NTAG + j];

    // ---- step 0 (exact analytic; trans[START,:]==NEG) ----
    float f_s0 = feats[(0 * BATCH + b) * NTAG + j];
    float m0 = mask[0 * BATCH + b];
    float alpha = (m0 > 0.0f) ? (NEG + log1pf(colsum) + f_s0)
                              : ((j == START_TAG) ? 0.0f : NEG);

    // ---- prefetch depth 2 ----
    float f0 = feats[(1 * BATCH + b) * NTAG + j];
    float mk0 = mask[1 * BATCH + b];
    float f1 = feats[(2 * BATCH + b) * NTAG + j];
    float mk1 = mask[2 * BATCH + b];

    for (int s = 1; s < SLEN; ++s) {
        const float fc = f0;
        const float mk = mk0;
        f0 = f1;
        mk0 = mk1;
        int sp = s + 2;
        if (sp >= SLEN) sp = SLEN - 1;
        f1 = feats[(sp * BATCH + b) * NTAG + j];
        mk1 = mask[sp * BATCH + b];

        // scaling constant: lane 0's alpha (cancels exactly; only range matters)
        float C = __uint_as_float(__builtin_amdgcn_readfirstlane(__float_as_uint(alpha)));
        float p = __expf(alpha - C);

        // acc_j = sum_i p_i * E[i][j]; p_i broadcast via readlane, 4 indep chains
        unsigned pu = __float_as_uint(p);
        float a0 = 0.0f, a1 = 0.0f, a2 = 0.0f, a3 = 0.0f;
#pragma unroll
        for (int i = 0; i < NTAG; i += 4) {
            a0 = fmaf(__uint_as_float(__builtin_amdgcn_readlane(pu, i + 0)), e[i + 0], a0);
            a1 = fmaf(__uint_as_float(__builtin_amdgcn_readlane(pu, i + 1)), e[i + 1], a1);
            a2 = fmaf(__uint_as_float(__builtin_amdgcn_readlane(pu, i + 2)), e[i + 2], a2);
            a3 = fmaf(__uint_as_float(__builtin_amdgcn_readlane(pu, i + 3)), e[i + 3], a3);
        }
        float acc = (a0 + a1) + (a2 + a3);

        float nxt = C + __logf(acc) + fc; // acc==0 (STOP col) -> -inf, benign
        alpha = (mk > 0.0f) ? nxt : alpha;
    }

    // ---- epilogue 1: log_z = logsumexp_j(alpha_j + trans[STOP][j]) ----
    float v = alpha + tstop;
    float m2 = v;
#pragma unroll
    for (int w = 32; w >= 1; w >>= 1)
        m2 = fmaxf(m2, __shfl_xor(m2, w, 64));
    float pe = __expf(v - m2);
#pragma unroll
    for (int w = 32; w >= 1; w >>= 1)
        pe += __shfl_xor(pe, w, 64);
    float logz = m2 + __logf(pe);

    // ---- epilogue 2: true-path score; lanes parallel over time steps ----
    // lane j handles s = j + 64k; all loads independent -> pipelined.
    float psc = 0.0f, pms = 0.0f;
#pragma unroll
    for (int k = 0; k < 8; ++k) {
        int s = j + 64 * k;
        int tg = tags[s * BATCH + b];
        float mk = mask[s * BATCH + b];
        int tprev = (s == 0) ? START_TAG : tags[(s - 1) * BATCH + b];
        float em = feats[(s * BATCH + b) * NTAG + tg];
        psc = fmaf(em + trans[tprev * NTAG + tg], mk, psc);
        pms += mk;
    }
#pragma unroll
    for (int w = 32; w >= 1; w >>= 1) {
        psc += __shfl_xor(psc, w, 64);
        pms += __shfl_xor(pms, w, 64);
    }

    if (j == 0) {
        int last_idx = (int)(pms + 0.5f) - 1;
        int ltag = tags[last_idx * BATCH + b];
        float score = psc + trans[ltag * NTAG + STOP_TAG];
        diff[b] = logz - score;
    }
}

__global__ __launch_bounds__(512) void crf_reduce(const float* __restrict__ diff,
                                                  float* __restrict__ out) {
    __shared__ float sdata[8];
    int t = threadIdx.x;
    float val = diff[t];
#pragma unroll
    for (int w = 32; w >= 1; w >>= 1)
        val += __shfl_xor(val, w, 64);
    if ((t & 63) == 0) sdata[t >> 6] = val;
    __syncthreads();
    if (t == 0) {
        float ssum = 0.0f;
        for (int i = 0; i < 8; ++i) ssum += sdata[i];
        out[0] = ssum * (1.0f / (float)BATCH);
    }
}

extern "C" void kernel_launch(void* const* d_in, const int* in_sizes, int n_in,
                              void* d_out, int out_size, void* d_ws, size_t ws_size,
                              hipStream_t stream) {
    const float* feats = (const float*)d_in[0];
    const int* tags = (const int*)d_in[1];
    const float* mask = (const float*)d_in[2];
    const float* trans = (const float*)d_in[3];
    float* out = (float*)d_out;
    float* diff = (float*)d_ws; // 512 floats

    crf_fwd<<<BATCH, 64, 0, stream>>>(feats, tags, mask, trans, diff);
    crf_reduce<<<1, 512, 0, stream>>>(diff, out);
}

// Round 5
// 242.243 us; speedup vs baseline: 2.0783x; 1.0726x over previous
//
#include <hip/hip_runtime.h>

#define NEG (-10000.0f)
#define START_TAG 62
#define STOP_TAG 63
#define SLEN 512
#define BATCH 512
#define NTAG 64

// One wave per batch; lane j = tag j.
// e[i] = exp(trans[i][j]) in VGPRs (amdgpu_waves_per_eu(1,1) -> full VGPR budget).
//
// Round-4 post-mortem: the loop's mask[sp*B+b] load is wave-uniform -> compiler
// emits SMEM s_load; SMEM is out-of-order so its consume forces s_waitcnt
// lgkmcnt(0), draining the just-issued prefetch -> ~600 stall cyc/step (same
// pathology as round 3's tags/trans scalar loads). Fix: preload the entire
// mask column into 8 VGPRs/lane (lane j holds mask[(64k+j)*B+b]); per step
// mk = v_readlane(mreg[k], s&63) -- k compile-time via 8x chunk unroll, lane
// index uniform SGPR. Hot loop now has exactly ONE vmcnt-tracked vector load
// (feats, depth-2 prefetch) -> precise vmcnt waits, zero steady-state stalls.
//
// Scaled linear-space recursion: p_i = exp(alpha_i - C), acc_j = sum_i p_i*E_ij,
// alpha'_j = C + log(acc_j) + f_j. C cancels exactly -> C = readfirstlane(alpha).
__global__ __launch_bounds__(64) __attribute__((amdgpu_waves_per_eu(1, 1)))
void crf_fwd(const float* __restrict__ feats,
             const int* __restrict__ tags,
             const float* __restrict__ mask,
             const float* __restrict__ trans,
             float* __restrict__ diff /* [BATCH] */) {
    const int b = blockIdx.x;
    const int j = threadIdx.x; // tag lane 0..63

    // ---- E column in registers + column sum (for exact analytic step 0) ----
    float e[NTAG];
    float colsum = 0.0f;
#pragma unroll
    for (int i = 0; i < NTAG; ++i) {
        e[i] = __expf(trans[i * NTAG + j]); // exp(NEG) underflows to 0 - desired
        colsum += e[i];
    }
    const float tstop = trans[STOP_TAG * NTAG + j];

    // ---- mask column preload: lane j holds mask[(64k+j)*B + b], k=0..7 ----
    float mreg[8];
#pragma unroll
    for (int k = 0; k < 8; ++k)
        mreg[k] = mask[(64 * k + j) * BATCH + b];

    // ---- step 0 (exact analytic; trans[START,:]==NEG) ----
    float f_s0 = feats[(0 * BATCH + b) * NTAG + j];
    float m0 = __uint_as_float(__builtin_amdgcn_readlane(__float_as_uint(mreg[0]), 0));
    float alpha = (m0 > 0.0f) ? (NEG + log1pf(colsum) + f_s0)
                              : ((j == START_TAG) ? 0.0f : NEG);

    // ---- feats prefetch depth 2 (the ONLY loads in the hot loop) ----
    const float* fp = feats + (size_t)b * NTAG + j;
    float f0 = fp[(size_t)1 * BATCH * NTAG];
    float f1 = fp[(size_t)2 * BATCH * NTAG];

#pragma unroll
    for (int k = 0; k < 8; ++k) {
        const float mcur = mreg[k]; // compile-time register index
        const int s_begin = (k == 0) ? 1 : 64 * k;
        const int s_end = 64 * k + 64;
        for (int s = s_begin; s < s_end; ++s) {
            const float fc = f0;
            f0 = f1;
            int sp = s + 2;
            if (sp > SLEN - 1) sp = SLEN - 1;
            f1 = fp[(size_t)sp * BATCH * NTAG];

            // mask broadcast from registers: uniform runtime lane index
            float mk = __uint_as_float(
                __builtin_amdgcn_readlane(__float_as_uint(mcur), s & 63));

            // scaling constant: lane 0's alpha (cancels exactly)
            float C = __uint_as_float(
                __builtin_amdgcn_readfirstlane(__float_as_uint(alpha)));
            float p = __expf(alpha - C);

            // acc_j = sum_i p_i * E[i][j]; readlane broadcast, 4 indep chains
            unsigned pu = __float_as_uint(p);
            float a0 = 0.0f, a1 = 0.0f, a2 = 0.0f, a3 = 0.0f;
#pragma unroll
            for (int i = 0; i < NTAG; i += 4) {
                a0 = fmaf(__uint_as_float(__builtin_amdgcn_readlane(pu, i + 0)), e[i + 0], a0);
                a1 = fmaf(__uint_as_float(__builtin_amdgcn_readlane(pu, i + 1)), e[i + 1], a1);
                a2 = fmaf(__uint_as_float(__builtin_amdgcn_readlane(pu, i + 2)), e[i + 2], a2);
                a3 = fmaf(__uint_as_float(__builtin_amdgcn_readlane(pu, i + 3)), e[i + 3], a3);
            }
            float acc = (a0 + a1) + (a2 + a3);

            float nxt = C + __logf(acc) + fc; // acc==0 (STOP col) -> -inf, benign
            alpha = (mk > 0.0f) ? nxt : alpha;
        }
    }

    // ---- epilogue 1: log_z = logsumexp_j(alpha_j + trans[STOP][j]) ----
    float v = alpha + tstop;
    float m2 = v;
#pragma unroll
    for (int w = 32; w >= 1; w >>= 1)
        m2 = fmaxf(m2, __shfl_xor(m2, w, 64));
    float pe = __expf(v - m2);
#pragma unroll
    for (int w = 32; w >= 1; w >>= 1)
        pe += __shfl_xor(pe, w, 64);
    float logz = m2 + __logf(pe);

    // ---- epilogue 2: true-path score; lanes parallel over time steps ----
    float psc = 0.0f, pms = 0.0f;
#pragma unroll
    for (int k = 0; k < 8; ++k) {
        int s = j + 64 * k;
        int tg = tags[s * BATCH + b];
        float mk = mreg[k]; // this lane's preloaded mask[s]
        int tprev = (s == 0) ? START_TAG : tags[(s - 1) * BATCH + b];
        float em = feats[((size_t)s * BATCH + b) * NTAG + tg];
        psc = fmaf(em + trans[tprev * NTAG + tg], mk, psc);
        pms += mk;
    }
#pragma unroll
    for (int w = 32; w >= 1; w >>= 1) {
        psc += __shfl_xor(psc, w, 64);
        pms += __shfl_xor(pms, w, 64);
    }

    if (j == 0) {
        int last_idx = (int)(pms + 0.5f) - 1;
        int ltag = tags[last_idx * BATCH + b];
        float score = psc + trans[ltag * NTAG + STOP_TAG];
        diff[b] = logz - score;
    }
}

__global__ __launch_bounds__(512) void crf_reduce(const float* __restrict__ diff,
                                                  float* __restrict__ out) {
    __shared__ float sdata[8];
    int t = threadIdx.x;
    float val = diff[t];
#pragma unroll
    for (int w = 32; w >= 1; w >>= 1)
        val += __shfl_xor(val, w, 64);
    if ((t & 63) == 0) sdata[t >> 6] = val;
    __syncthreads();
    if (t == 0) {
        float ssum = 0.0f;
        for (int i = 0; i < 8; ++i) ssum += sdata[i];
        out[0] = ssum * (1.0f / (float)BATCH);
    }
}

extern "C" void kernel_launch(void* const* d_in, const int* in_sizes, int n_in,
                              void* d_out, int out_size, void* d_ws, size_t ws_size,
                              hipStream_t stream) {
    const float* feats = (const float*)d_in[0];
    const int* tags = (const int*)d_in[1];
    const float* mask = (const float*)d_in[2];
    const float* trans = (const float*)d_in[3];
    float* out = (float*)d_out;
    float* diff = (float*)d_ws; // 512 floats

    crf_fwd<<<BATCH, 64, 0, stream>>>(feats, tags, mask, trans, diff);
    crf_reduce<<<1, 512, 0, stream>>>(diff, out);
}